// Round 1
// baseline (2037.654 us; speedup 1.0000x reference)
//
#include <hip/hip_runtime.h>

// Output layout (flat, concatenated in reference return order):
//   forces : n_atoms*3 floats
//   virial : n_images*9 floats
//   stress : n_images*9 floats

__global__ __launch_bounds__(256) void edge_kernel(
    const float* __restrict__ edge_diff,   // [n_edges*3]
    const float* __restrict__ dE_ddiff,    // [n_edges*3]
    const int2*  __restrict__ edge_idx,    // [n_edges] (i,j)
    const int*   __restrict__ image_idx,   // [n_atoms]
    float* __restrict__ forces,            // [n_atoms*3]  (pre-zeroed)
    float* __restrict__ virial,            // [n_images*9] (pre-zeroed)
    int n_edges, int n_images)
{
    extern __shared__ float lds_v[];       // n_images*9
    const int nv = n_images * 9;
    for (int t = threadIdx.x; t < nv; t += blockDim.x) lds_v[t] = 0.f;
    __syncthreads();

    const int stride = gridDim.x * blockDim.x;
    for (int e = blockIdx.x * blockDim.x + threadIdx.x; e < n_edges; e += stride) {
        const int2 ij = edge_idx[e];
        const int i = ij.x;
        const int j = ij.y;

        const float dx = dE_ddiff[3*e + 0];
        const float dy = dE_ddiff[3*e + 1];
        const float dz = dE_ddiff[3*e + 2];

        // forces[i] += dE ; forces[j] -= dE
        unsafeAtomicAdd(&forces[3*i + 0],  dx);
        unsafeAtomicAdd(&forces[3*i + 1],  dy);
        unsafeAtomicAdd(&forces[3*i + 2],  dz);
        unsafeAtomicAdd(&forces[3*j + 0], -dx);
        unsafeAtomicAdd(&forces[3*j + 1], -dy);
        unsafeAtomicAdd(&forces[3*j + 2], -dz);

        const float ex = edge_diff[3*e + 0];
        const float ey = edge_diff[3*e + 1];
        const float ez = edge_diff[3*e + 2];

        const int img = image_idx[i];
        float* v = &lds_v[img * 9];
        unsafeAtomicAdd(&v[0], ex * dx);
        unsafeAtomicAdd(&v[1], ex * dy);
        unsafeAtomicAdd(&v[2], ex * dz);
        unsafeAtomicAdd(&v[3], ey * dx);
        unsafeAtomicAdd(&v[4], ey * dy);
        unsafeAtomicAdd(&v[5], ey * dz);
        unsafeAtomicAdd(&v[6], ez * dx);
        unsafeAtomicAdd(&v[7], ez * dy);
        unsafeAtomicAdd(&v[8], ez * dz);
    }
    __syncthreads();

    // Flush block-local virial partial sums to global.
    for (int t = threadIdx.x; t < nv; t += blockDim.x) {
        const float val = lds_v[t];
        if (val != 0.f) unsafeAtomicAdd(&virial[t], val);
    }
}

__global__ void stress_kernel(const float* __restrict__ cell,   // [n_images*9]
                              const float* __restrict__ virial, // [n_images*9]
                              float* __restrict__ stress,       // [n_images*9]
                              int n_images)
{
    const int i = blockIdx.x * blockDim.x + threadIdx.x;
    if (i >= n_images) return;
    const float* c = &cell[i * 9];
    // volume = dot(c0, cross(c1, c2))
    const float crx = c[4] * c[8] - c[5] * c[7];
    const float cry = c[5] * c[6] - c[3] * c[8];
    const float crz = c[3] * c[7] - c[4] * c[6];
    const float vol = c[0] * crx + c[1] * cry + c[2] * crz;
    const float scale = -1.0f / vol;
    #pragma unroll
    for (int k = 0; k < 9; ++k)
        stress[i * 9 + k] = virial[i * 9 + k] * scale;
}

extern "C" void kernel_launch(void* const* d_in, const int* in_sizes, int n_in,
                              void* d_out, int out_size, void* d_ws, size_t ws_size,
                              hipStream_t stream)
{
    const float* edge_diff = (const float*)d_in[0];
    const float* dE_ddiff  = (const float*)d_in[1];
    const float* cell      = (const float*)d_in[2];
    const int2*  edge_idx  = (const int2*)d_in[3];
    const int*   image_idx = (const int*)d_in[4];

    const int n_edges  = in_sizes[0] / 3;
    const int n_images = in_sizes[2] / 9;
    const int n_atoms  = in_sizes[4];

    float* out    = (float*)d_out;
    float* forces = out;
    float* virial = out + (size_t)n_atoms * 3;
    float* stress = virial + (size_t)n_images * 9;

    // Zero the accumulated outputs (harness poisons d_out with 0xAA).
    hipMemsetAsync(out, 0, ((size_t)n_atoms * 3 + (size_t)n_images * 9) * sizeof(float), stream);

    const int threads = 256;
    const int blocks  = 2048;            // grid-stride; 8 blocks/CU, bounds virial flush atomics
    const size_t lds  = (size_t)n_images * 9 * sizeof(float);
    edge_kernel<<<blocks, threads, lds, stream>>>(edge_diff, dE_ddiff, edge_idx, image_idx,
                                                  forces, virial, n_edges, n_images);

    stress_kernel<<<(n_images + 63) / 64, 64, 0, stream>>>(cell, virial, stress, n_images);
}

// Round 2
// 2018.879 us; speedup vs baseline: 1.0093x; 1.0093x over previous
//
#include <hip/hip_runtime.h>

// Output layout (flat, concatenated in reference return order):
//   forces : n_atoms*3 floats
//   virial : n_images*9 floats
//   stress : n_images*9 floats
//
// Strategy (round 2): agent-scope fp32 atomics on gfx950 write through L2 to
// the fabric coherent point (~20 G atomics/s, measured 32 B HBM write per
// atomic). Instead: 8 per-XCD private copies of forces/virial in d_ws,
// updated with plain global_atomic_add_f32 (no sc bits -> executes in the
// XCD-local TCC, line stays in L2). Block identifies its XCD via
// HW_REG_XCC_ID. Reduce kernel sums the 8 copies.

#define NCOPY 8

__device__ __forceinline__ void l2_fadd(float* p, float v) {
    // No sc0/sc1: XCD-local L2 atomic, no write-through.
    asm volatile("global_atomic_add_f32 %0, %1, off" :: "v"(p), "v"(v) : "memory");
}

__device__ __forceinline__ unsigned xcc_id() {
    unsigned x;
    asm volatile("s_getreg_b32 %0, hwreg(HW_REG_XCC_ID)" : "=s"(x));
    return x & (NCOPY - 1);
}

__global__ __launch_bounds__(256) void edge_kernel_l2(
    const float* __restrict__ edge_diff,   // [n_edges*3]
    const float* __restrict__ dE_ddiff,    // [n_edges*3]
    const int2*  __restrict__ edge_idx,    // [n_edges] (i,j)
    const int*   __restrict__ image_idx,   // [n_atoms]
    float* __restrict__ fcopies,           // [NCOPY][n_atoms*3]  (zeroed)
    float* __restrict__ vcopies,           // [NCOPY][n_images*9] (zeroed)
    int n_edges, int n_images, int n_atoms)
{
    extern __shared__ float lds_v[];       // n_images*9
    const int nv = n_images * 9;
    for (int t = threadIdx.x; t < nv; t += blockDim.x) lds_v[t] = 0.f;
    __syncthreads();

    const unsigned xcc = xcc_id();
    float* __restrict__ F = fcopies + (size_t)xcc * (size_t)n_atoms * 3;

    const int stride = gridDim.x * blockDim.x;
    for (int e = blockIdx.x * blockDim.x + threadIdx.x; e < n_edges; e += stride) {
        const int2 ij = edge_idx[e];
        const int i = ij.x;
        const int j = ij.y;

        const float dx = dE_ddiff[3*e + 0];
        const float dy = dE_ddiff[3*e + 1];
        const float dz = dE_ddiff[3*e + 2];

        l2_fadd(&F[3*i + 0],  dx);
        l2_fadd(&F[3*i + 1],  dy);
        l2_fadd(&F[3*i + 2],  dz);
        l2_fadd(&F[3*j + 0], -dx);
        l2_fadd(&F[3*j + 1], -dy);
        l2_fadd(&F[3*j + 2], -dz);

        const float ex = edge_diff[3*e + 0];
        const float ey = edge_diff[3*e + 1];
        const float ez = edge_diff[3*e + 2];

        const int img = image_idx[i];
        float* v = &lds_v[img * 9];
        atomicAdd(&v[0], ex * dx);
        atomicAdd(&v[1], ex * dy);
        atomicAdd(&v[2], ex * dz);
        atomicAdd(&v[3], ey * dx);
        atomicAdd(&v[4], ey * dy);
        atomicAdd(&v[5], ey * dz);
        atomicAdd(&v[6], ez * dx);
        atomicAdd(&v[7], ez * dy);
        atomicAdd(&v[8], ez * dz);
    }
    __syncthreads();

    float* __restrict__ V = vcopies + (size_t)xcc * nv;
    for (int t = threadIdx.x; t < nv; t += blockDim.x) {
        const float val = lds_v[t];
        if (val != 0.f) l2_fadd(&V[t], val);
    }
}

// Sum the NCOPY force copies -> d_out forces (vectorized float4).
__global__ __launch_bounds__(256) void reduce_forces_kernel(
    const float4* __restrict__ fcopies, float4* __restrict__ forces,
    int n4 /* = n_atoms*3/4 */, int stride4 /* = n_atoms*3/4 */)
{
    const int gstride = gridDim.x * blockDim.x;
    for (int t = blockIdx.x * blockDim.x + threadIdx.x; t < n4; t += gstride) {
        float4 s = fcopies[t];
        #pragma unroll
        for (int c = 1; c < NCOPY; ++c) {
            float4 a = fcopies[(size_t)c * stride4 + t];
            s.x += a.x; s.y += a.y; s.z += a.z; s.w += a.w;
        }
        forces[t] = s;
    }
}

// Sum virial copies, write virial and stress.
__global__ void virial_stress_kernel(
    const float* __restrict__ vcopies, const float* __restrict__ cell,
    float* __restrict__ virial, float* __restrict__ stress, int n_images)
{
    const int t = blockIdx.x * blockDim.x + threadIdx.x;
    const int nv = n_images * 9;
    if (t >= nv) return;
    float s = 0.f;
    #pragma unroll
    for (int c = 0; c < NCOPY; ++c) s += vcopies[(size_t)c * nv + t];
    virial[t] = s;

    const int img = t / 9;
    const float* cc = &cell[img * 9];
    const float crx = cc[4] * cc[8] - cc[5] * cc[7];
    const float cry = cc[5] * cc[6] - cc[3] * cc[8];
    const float crz = cc[3] * cc[7] - cc[4] * cc[6];
    const float vol = cc[0] * crx + cc[1] * cry + cc[2] * crz;
    stress[t] = s * (-1.0f / vol);
}

// ---------------- fallback (round-1) path ----------------
__global__ __launch_bounds__(256) void edge_kernel_fb(
    const float* __restrict__ edge_diff, const float* __restrict__ dE_ddiff,
    const int2* __restrict__ edge_idx, const int* __restrict__ image_idx,
    float* __restrict__ forces, float* __restrict__ virial,
    int n_edges, int n_images)
{
    extern __shared__ float lds_v[];
    const int nv = n_images * 9;
    for (int t = threadIdx.x; t < nv; t += blockDim.x) lds_v[t] = 0.f;
    __syncthreads();
    const int stride = gridDim.x * blockDim.x;
    for (int e = blockIdx.x * blockDim.x + threadIdx.x; e < n_edges; e += stride) {
        const int2 ij = edge_idx[e];
        const int i = ij.x, j = ij.y;
        const float dx = dE_ddiff[3*e+0], dy = dE_ddiff[3*e+1], dz = dE_ddiff[3*e+2];
        unsafeAtomicAdd(&forces[3*i+0],  dx);
        unsafeAtomicAdd(&forces[3*i+1],  dy);
        unsafeAtomicAdd(&forces[3*i+2],  dz);
        unsafeAtomicAdd(&forces[3*j+0], -dx);
        unsafeAtomicAdd(&forces[3*j+1], -dy);
        unsafeAtomicAdd(&forces[3*j+2], -dz);
        const float ex = edge_diff[3*e+0], ey = edge_diff[3*e+1], ez = edge_diff[3*e+2];
        const int img = image_idx[i];
        float* v = &lds_v[img * 9];
        atomicAdd(&v[0], ex*dx); atomicAdd(&v[1], ex*dy); atomicAdd(&v[2], ex*dz);
        atomicAdd(&v[3], ey*dx); atomicAdd(&v[4], ey*dy); atomicAdd(&v[5], ey*dz);
        atomicAdd(&v[6], ez*dx); atomicAdd(&v[7], ez*dy); atomicAdd(&v[8], ez*dz);
    }
    __syncthreads();
    for (int t = threadIdx.x; t < nv; t += blockDim.x) {
        const float val = lds_v[t];
        if (val != 0.f) unsafeAtomicAdd(&virial[t], val);
    }
}

__global__ void stress_kernel_fb(const float* __restrict__ cell,
                                 const float* __restrict__ virial,
                                 float* __restrict__ stress, int n_images)
{
    const int i = blockIdx.x * blockDim.x + threadIdx.x;
    if (i >= n_images) return;
    const float* c = &cell[i * 9];
    const float crx = c[4]*c[8] - c[5]*c[7];
    const float cry = c[5]*c[6] - c[3]*c[8];
    const float crz = c[3]*c[7] - c[4]*c[6];
    const float vol = c[0]*crx + c[1]*cry + c[2]*crz;
    #pragma unroll
    for (int k = 0; k < 9; ++k) stress[i*9+k] = virial[i*9+k] * (-1.0f/vol);
}

extern "C" void kernel_launch(void* const* d_in, const int* in_sizes, int n_in,
                              void* d_out, int out_size, void* d_ws, size_t ws_size,
                              hipStream_t stream)
{
    const float* edge_diff = (const float*)d_in[0];
    const float* dE_ddiff  = (const float*)d_in[1];
    const float* cell      = (const float*)d_in[2];
    const int2*  edge_idx  = (const int2*)d_in[3];
    const int*   image_idx = (const int*)d_in[4];

    const int n_edges  = in_sizes[0] / 3;
    const int n_images = in_sizes[2] / 9;
    const int n_atoms  = in_sizes[4];

    float* out    = (float*)d_out;
    float* forces = out;
    float* virial = out + (size_t)n_atoms * 3;
    float* stress = virial + (size_t)n_images * 9;

    const size_t fcop_elems = (size_t)NCOPY * n_atoms * 3;
    const size_t vcop_elems = (size_t)NCOPY * n_images * 9;
    const size_t need = (fcop_elems + vcop_elems) * sizeof(float);

    const int threads = 256;
    const int blocks  = 2048;
    const size_t lds  = (size_t)n_images * 9 * sizeof(float);

    if (ws_size >= need) {
        float* fcopies = (float*)d_ws;
        float* vcopies = fcopies + fcop_elems;
        hipMemsetAsync(d_ws, 0, need, stream);

        edge_kernel_l2<<<blocks, threads, lds, stream>>>(
            edge_diff, dE_ddiff, edge_idx, image_idx,
            fcopies, vcopies, n_edges, n_images, n_atoms);

        const int n4 = (n_atoms * 3) / 4;   // 600000/4, exact
        reduce_forces_kernel<<<(n4 + 255) / 256, 256, 0, stream>>>(
            (const float4*)fcopies, (float4*)forces, n4, n4);

        const int nv = n_images * 9;
        virial_stress_kernel<<<(nv + 255) / 256, 256, 0, stream>>>(
            vcopies, cell, virial, stress, n_images);
    } else {
        hipMemsetAsync(out, 0, ((size_t)n_atoms * 3 + (size_t)n_images * 9) * sizeof(float), stream);
        edge_kernel_fb<<<blocks, threads, lds, stream>>>(
            edge_diff, dE_ddiff, edge_idx, image_idx, forces, virial, n_edges, n_images);
        stress_kernel_fb<<<(n_images + 63) / 64, 64, 0, stream>>>(cell, virial, stress, n_images);
    }
}

// Round 3
// 822.957 us; speedup vs baseline: 2.4760x; 2.4532x over previous
//
#include <hip/hip_runtime.h>

// Output layout (flat): forces[n_atoms*3] | virial[n_images*9] | stress[n_images*9]
//
// v3: global fp32 atomics on gfx950 write through to the fabric coherent point
// (32 B/atomic, ~706 GB/s ceiling -> 20 G atomics/s; proven by WRITE_SIZE in
// rounds 1-2). So eliminate them: bin edge contributions by atom-bucket
// (1024 atoms/bucket) into an exact-layout entry array (count + scan +
// scatter via LDS cursors), then gather per bucket into an LDS force tile.
// Only ~295k global atomics remain (virial flush).

typedef unsigned int uint;

#define SLICES 256          // scatter/count blocks; slice = contiguous edge range
#define NBMAX  256          // max buckets (n_atoms <= 256*1024)
#define BASHIFT 10          // 1024 atoms per bucket
#define NVMAX  1152         // n_images*9 cap (128 images)

// ---------------- K1: per-(slice,bucket) histogram ----------------
__global__ __launch_bounds__(256) void k_count(
    const int2* __restrict__ edge_idx, uint* __restrict__ counts,
    int n_edges, int es, int nb)
{
    __shared__ uint hist[NBMAX];
    for (int t = threadIdx.x; t < nb; t += blockDim.x) hist[t] = 0;
    __syncthreads();
    const int s  = blockIdx.x;
    const int e0 = s * es;
    const int e1 = min(n_edges, e0 + es);
    for (int e = e0 + threadIdx.x; e < e1; e += blockDim.x) {
        const int2 ij = edge_idx[e];
        atomicAdd(&hist[((uint)ij.x) >> BASHIFT], 1u);
        atomicAdd(&hist[((uint)ij.y) >> BASHIFT], 1u);
    }
    __syncthreads();
    for (int b = threadIdx.x; b < nb; b += blockDim.x)
        counts[(size_t)b * SLICES + s] = hist[b];   // bucket-major
}

// ---------------- K2: in-place exclusive scan (single block) ----------------
__global__ __launch_bounds__(1024) void k_scan(uint* __restrict__ a, int n)
{
    __shared__ uint psum[1024];
    const int chunk = (n + 1023) >> 10;
    const int lo = threadIdx.x * chunk;
    const int hi = min(n, lo + chunk);
    uint s = 0;
    for (int k = lo; k < hi; ++k) s += a[k];
    psum[threadIdx.x] = s;
    __syncthreads();
    for (int off = 1; off < 1024; off <<= 1) {
        uint v = (threadIdx.x >= off) ? psum[threadIdx.x - off] : 0u;
        __syncthreads();
        psum[threadIdx.x] += v;
        __syncthreads();
    }
    uint run = (threadIdx.x > 0) ? psum[threadIdx.x - 1] : 0u;
    for (int k = lo; k < hi; ++k) { uint c = a[k]; a[k] = run; run += c; }
}

// ---------------- K3: scatter entries + virial ----------------
__global__ __launch_bounds__(256) void k_scatter(
    const float* __restrict__ edge_diff, const float* __restrict__ dE_ddiff,
    const int2* __restrict__ edge_idx, const int* __restrict__ image_idx,
    const uint* __restrict__ offsets, float4* __restrict__ entries,
    float* __restrict__ virial /* zeroed */, int n_edges, int es, int nb, int nv)
{
    __shared__ uint  cur[NBMAX];
    __shared__ float lv[NVMAX];
    const int s = blockIdx.x;
    for (int t = threadIdx.x; t < nb; t += blockDim.x)
        cur[t] = offsets[(size_t)t * SLICES + s];
    for (int t = threadIdx.x; t < nv; t += blockDim.x) lv[t] = 0.f;
    __syncthreads();

    const int e0 = s * es;
    const int e1 = min(n_edges, e0 + es);
    for (int e = e0 + threadIdx.x; e < e1; e += blockDim.x) {
        const int2 ij = edge_idx[e];
        const float dx = dE_ddiff[3*e + 0];
        const float dy = dE_ddiff[3*e + 1];
        const float dz = dE_ddiff[3*e + 2];

        const uint pi = atomicAdd(&cur[((uint)ij.x) >> BASHIFT], 1u);
        entries[pi] = make_float4(dx, dy, dz, __uint_as_float((uint)ij.x));
        const uint pj = atomicAdd(&cur[((uint)ij.y) >> BASHIFT], 1u);
        entries[pj] = make_float4(-dx, -dy, -dz, __uint_as_float((uint)ij.y));

        const float ex = edge_diff[3*e + 0];
        const float ey = edge_diff[3*e + 1];
        const float ez = edge_diff[3*e + 2];
        float* v = &lv[image_idx[ij.x] * 9];
        atomicAdd(&v[0], ex*dx); atomicAdd(&v[1], ex*dy); atomicAdd(&v[2], ex*dz);
        atomicAdd(&v[3], ey*dx); atomicAdd(&v[4], ey*dy); atomicAdd(&v[5], ey*dz);
        atomicAdd(&v[6], ez*dx); atomicAdd(&v[7], ez*dy); atomicAdd(&v[8], ez*dz);
    }
    __syncthreads();
    for (int t = threadIdx.x; t < nv; t += blockDim.x) {
        const float val = lv[t];
        if (val != 0.f) unsafeAtomicAdd(&virial[t], val);
    }
}

// ---------------- K4: gather per bucket -> forces (no atomics) ----------------
__global__ __launch_bounds__(256) void k_gather(
    const float4* __restrict__ entries, const uint* __restrict__ offsets,
    float* __restrict__ forces, int n_atoms, int nb, uint total)
{
    __shared__ float tile[3 << BASHIFT];     // 1024*3 floats
    const int q = blockIdx.x;
    for (int t = threadIdx.x; t < (3 << BASHIFT); t += blockDim.x) tile[t] = 0.f;
    __syncthreads();

    const uint beg = offsets[(size_t)q * SLICES];
    const uint end = (q + 1 < nb) ? offsets[(size_t)(q + 1) * SLICES] : total;
    for (uint k = beg + threadIdx.x; k < end; k += blockDim.x) {
        const float4 ent = entries[k];
        const uint local = __float_as_uint(ent.w) & ((1u << BASHIFT) - 1u);
        atomicAdd(&tile[local*3 + 0], ent.x);
        atomicAdd(&tile[local*3 + 1], ent.y);
        atomicAdd(&tile[local*3 + 2], ent.z);
    }
    __syncthreads();

    const int base = q << BASHIFT;
    const int lim3 = min(n_atoms - base, 1 << BASHIFT) * 3;
    for (int t = threadIdx.x; t < lim3; t += blockDim.x)
        forces[(size_t)base * 3 + t] = tile[t];
}

// ---------------- K5: stress ----------------
__global__ void k_stress(const float* __restrict__ cell,
                         const float* __restrict__ virial,
                         float* __restrict__ stress, int n_images)
{
    const int t = blockIdx.x * blockDim.x + threadIdx.x;
    if (t >= n_images * 9) return;
    const float* c = &cell[(t / 9) * 9];
    const float crx = c[4]*c[8] - c[5]*c[7];
    const float cry = c[5]*c[6] - c[3]*c[8];
    const float crz = c[3]*c[7] - c[4]*c[6];
    const float vol = c[0]*crx + c[1]*cry + c[2]*crz;
    stress[t] = virial[t] * (-1.0f / vol);
}

// ---------------- fallback (round-1) path ----------------
__global__ __launch_bounds__(256) void edge_kernel_fb(
    const float* __restrict__ edge_diff, const float* __restrict__ dE_ddiff,
    const int2* __restrict__ edge_idx, const int* __restrict__ image_idx,
    float* __restrict__ forces, float* __restrict__ virial,
    int n_edges, int n_images)
{
    extern __shared__ float lds_v[];
    const int nv = n_images * 9;
    for (int t = threadIdx.x; t < nv; t += blockDim.x) lds_v[t] = 0.f;
    __syncthreads();
    const int stride = gridDim.x * blockDim.x;
    for (int e = blockIdx.x * blockDim.x + threadIdx.x; e < n_edges; e += stride) {
        const int2 ij = edge_idx[e];
        const int i = ij.x, j = ij.y;
        const float dx = dE_ddiff[3*e+0], dy = dE_ddiff[3*e+1], dz = dE_ddiff[3*e+2];
        unsafeAtomicAdd(&forces[3*i+0],  dx);
        unsafeAtomicAdd(&forces[3*i+1],  dy);
        unsafeAtomicAdd(&forces[3*i+2],  dz);
        unsafeAtomicAdd(&forces[3*j+0], -dx);
        unsafeAtomicAdd(&forces[3*j+1], -dy);
        unsafeAtomicAdd(&forces[3*j+2], -dz);
        const float ex = edge_diff[3*e+0], ey = edge_diff[3*e+1], ez = edge_diff[3*e+2];
        float* v = &lds_v[image_idx[i] * 9];
        atomicAdd(&v[0], ex*dx); atomicAdd(&v[1], ex*dy); atomicAdd(&v[2], ex*dz);
        atomicAdd(&v[3], ey*dx); atomicAdd(&v[4], ey*dy); atomicAdd(&v[5], ey*dz);
        atomicAdd(&v[6], ez*dx); atomicAdd(&v[7], ez*dy); atomicAdd(&v[8], ez*dz);
    }
    __syncthreads();
    for (int t = threadIdx.x; t < nv; t += blockDim.x) {
        const float val = lds_v[t];
        if (val != 0.f) unsafeAtomicAdd(&virial[t], val);
    }
}

extern "C" void kernel_launch(void* const* d_in, const int* in_sizes, int n_in,
                              void* d_out, int out_size, void* d_ws, size_t ws_size,
                              hipStream_t stream)
{
    const float* edge_diff = (const float*)d_in[0];
    const float* dE_ddiff  = (const float*)d_in[1];
    const float* cell      = (const float*)d_in[2];
    const int2*  edge_idx  = (const int2*)d_in[3];
    const int*   image_idx = (const int*)d_in[4];

    const int n_edges  = in_sizes[0] / 3;
    const int n_images = in_sizes[2] / 9;
    const int n_atoms  = in_sizes[4];
    const int nv       = n_images * 9;

    float* out    = (float*)d_out;
    float* forces = out;
    float* virial = out + (size_t)n_atoms * 3;
    float* stress = virial + nv;

    const int nb = (n_atoms + (1 << BASHIFT) - 1) >> BASHIFT;
    const int es = (n_edges + SLICES - 1) / SLICES;
    const uint total = (uint)(2 * (size_t)n_edges);

    const size_t entries_bytes = (size_t)total * sizeof(float4);
    const size_t counts_bytes  = (size_t)nb * SLICES * sizeof(uint);
    const size_t need = entries_bytes + counts_bytes;

    if (ws_size >= need && nb <= NBMAX && nv <= NVMAX) {
        float4* entries = (float4*)d_ws;
        uint*   offsets = (uint*)((char*)d_ws + entries_bytes);

        hipMemsetAsync(virial, 0, nv * sizeof(float), stream);

        k_count<<<SLICES, 256, 0, stream>>>(edge_idx, offsets, n_edges, es, nb);
        k_scan<<<1, 1024, 0, stream>>>(offsets, nb * SLICES);
        k_scatter<<<SLICES, 256, 0, stream>>>(edge_diff, dE_ddiff, edge_idx, image_idx,
                                              offsets, entries, virial, n_edges, es, nb, nv);
        k_gather<<<nb, 256, 0, stream>>>(entries, offsets, forces, n_atoms, nb, total);
        k_stress<<<(nv + 255) / 256, 256, 0, stream>>>(cell, virial, stress, n_images);
    } else {
        hipMemsetAsync(out, 0, ((size_t)n_atoms * 3 + nv) * sizeof(float), stream);
        edge_kernel_fb<<<2048, 256, nv * sizeof(float), stream>>>(
            edge_diff, dE_ddiff, edge_idx, image_idx, forces, virial, n_edges, n_images);
        k_stress<<<(nv + 255) / 256, 256, 0, stream>>>(cell, virial, stress, n_images);
    }
}

// Round 4
// 726.718 us; speedup vs baseline: 2.8039x; 1.1324x over previous
//
#include <hip/hip_runtime.h>

// Output layout (flat): forces[n_atoms*3] | virial[n_images*9] | stress[n_images*9]
//
// v4: round-3 structure (count/scan/scatter/gather, zero force global atomics)
// was latency-bound at 11.6% occupancy (256 one-wavefront... 1-block/CU grids).
// Fix parallelism: 1024-thread count/scatter blocks (16 waves/CU), 256-atom
// buckets (782 gather blocks, 3/CU), hierarchical parallel scan instead of a
// single-block serial scan.

typedef unsigned int uint;

#define SLICES  256         // count/scatter blocks (1024 threads each)
#define BASHIFT 8           // 256 atoms per bucket
#define NBCAP   1024        // max buckets (n_atoms <= 256k)
#define NVMAX   1152        // n_images*9 cap (128 images)

// ---------------- K1: per-(slice,bucket) histogram ----------------
__global__ __launch_bounds__(1024) void k_count(
    const int2* __restrict__ edge_idx, uint* __restrict__ counts,
    int n_edges, int es, int nb)
{
    __shared__ uint hist[NBCAP];
    for (int t = threadIdx.x; t < nb; t += blockDim.x) hist[t] = 0;
    __syncthreads();
    const int s  = blockIdx.x;
    const int e0 = s * es;
    const int e1 = min(n_edges, e0 + es);
    for (int e = e0 + threadIdx.x; e < e1; e += blockDim.x) {
        const int2 ij = edge_idx[e];
        atomicAdd(&hist[((uint)ij.x) >> BASHIFT], 1u);
        atomicAdd(&hist[((uint)ij.y) >> BASHIFT], 1u);
    }
    __syncthreads();
    for (int b = threadIdx.x; b < nb; b += blockDim.x)
        counts[(size_t)b * SLICES + s] = hist[b];   // bucket-major
}

// ---------------- K2a: row sums (one block per bucket) ----------------
__global__ __launch_bounds__(SLICES) void k_rowsum(
    const uint* __restrict__ counts, uint* __restrict__ rowsum)
{
    __shared__ uint red[SLICES];
    const int b = blockIdx.x;
    red[threadIdx.x] = counts[(size_t)b * SLICES + threadIdx.x];
    __syncthreads();
    for (int off = SLICES / 2; off > 0; off >>= 1) {
        if (threadIdx.x < off) red[threadIdx.x] += red[threadIdx.x + off];
        __syncthreads();
    }
    if (threadIdx.x == 0) rowsum[b] = red[0];
}

// ---------------- K2b: exclusive scan of row sums (single block) --------
__global__ __launch_bounds__(1024) void k_scan_rows(
    const uint* __restrict__ rowsum, uint* __restrict__ rowoff, int nb)
{
    __shared__ uint psum[1024];
    const int t = threadIdx.x;
    psum[t] = (t < nb) ? rowsum[t] : 0u;
    __syncthreads();
    for (int off = 1; off < 1024; off <<= 1) {
        uint v = (t >= off) ? psum[t - off] : 0u;
        __syncthreads();
        psum[t] += v;
        __syncthreads();
    }
    if (t < nb) rowoff[t] = (t == 0) ? 0u : psum[t - 1];
}

// ---------------- K2c: per-row exclusive scan + global offset ----------
__global__ __launch_bounds__(SLICES) void k_rowscan(
    uint* __restrict__ counts, const uint* __restrict__ rowoff)
{
    __shared__ uint psum[SLICES];
    const int b = blockIdx.x;
    const int t = threadIdx.x;
    const uint c = counts[(size_t)b * SLICES + t];
    psum[t] = c;
    __syncthreads();
    for (int off = 1; off < SLICES; off <<= 1) {
        uint v = (t >= off) ? psum[t - off] : 0u;
        __syncthreads();
        psum[t] += v;
        __syncthreads();
    }
    counts[(size_t)b * SLICES + t] = rowoff[b] + psum[t] - c;  // exclusive
}

// ---------------- K3: scatter entries + virial ----------------
__global__ __launch_bounds__(1024) void k_scatter(
    const float* __restrict__ edge_diff, const float* __restrict__ dE_ddiff,
    const int2* __restrict__ edge_idx, const int* __restrict__ image_idx,
    const uint* __restrict__ offsets, float4* __restrict__ entries,
    float* __restrict__ virial /* zeroed */, int n_edges, int es, int nb, int nv)
{
    __shared__ uint  cur[NBCAP];
    __shared__ float lv[NVMAX];
    const int s = blockIdx.x;
    for (int t = threadIdx.x; t < nb; t += blockDim.x)
        cur[t] = offsets[(size_t)t * SLICES + s];
    for (int t = threadIdx.x; t < nv; t += blockDim.x) lv[t] = 0.f;
    __syncthreads();

    const int e0 = s * es;
    const int e1 = min(n_edges, e0 + es);
    for (int e = e0 + threadIdx.x; e < e1; e += blockDim.x) {
        const int2 ij = edge_idx[e];
        const float dx = dE_ddiff[3*e + 0];
        const float dy = dE_ddiff[3*e + 1];
        const float dz = dE_ddiff[3*e + 2];

        const uint pi = atomicAdd(&cur[((uint)ij.x) >> BASHIFT], 1u);
        entries[pi] = make_float4(dx, dy, dz, __uint_as_float((uint)ij.x));
        const uint pj = atomicAdd(&cur[((uint)ij.y) >> BASHIFT], 1u);
        entries[pj] = make_float4(-dx, -dy, -dz, __uint_as_float((uint)ij.y));

        const float ex = edge_diff[3*e + 0];
        const float ey = edge_diff[3*e + 1];
        const float ez = edge_diff[3*e + 2];
        float* v = &lv[image_idx[ij.x] * 9];
        atomicAdd(&v[0], ex*dx); atomicAdd(&v[1], ex*dy); atomicAdd(&v[2], ex*dz);
        atomicAdd(&v[3], ey*dx); atomicAdd(&v[4], ey*dy); atomicAdd(&v[5], ey*dz);
        atomicAdd(&v[6], ez*dx); atomicAdd(&v[7], ez*dy); atomicAdd(&v[8], ez*dz);
    }
    __syncthreads();
    for (int t = threadIdx.x; t < nv; t += blockDim.x) {
        const float val = lv[t];
        if (val != 0.f) unsafeAtomicAdd(&virial[t], val);
    }
}

// ---------------- K4: gather per bucket -> forces (no global atomics) ----
__global__ __launch_bounds__(256) void k_gather(
    const float4* __restrict__ entries, const uint* __restrict__ offsets,
    float* __restrict__ forces, int n_atoms, int nb, uint total)
{
    __shared__ float tile[3 << BASHIFT];     // 256*3 floats = 3 KB
    const int q = blockIdx.x;
    for (int t = threadIdx.x; t < (3 << BASHIFT); t += blockDim.x) tile[t] = 0.f;
    __syncthreads();

    const uint beg = offsets[(size_t)q * SLICES];
    const uint end = (q + 1 < nb) ? offsets[(size_t)(q + 1) * SLICES] : total;
    for (uint k = beg + threadIdx.x; k < end; k += blockDim.x) {
        const float4 ent = entries[k];
        const uint local = __float_as_uint(ent.w) & ((1u << BASHIFT) - 1u);
        atomicAdd(&tile[local*3 + 0], ent.x);
        atomicAdd(&tile[local*3 + 1], ent.y);
        atomicAdd(&tile[local*3 + 2], ent.z);
    }
    __syncthreads();

    const int base = q << BASHIFT;
    const int lim3 = min(n_atoms - base, 1 << BASHIFT) * 3;
    for (int t = threadIdx.x; t < lim3; t += blockDim.x)
        forces[(size_t)base * 3 + t] = tile[t];
}

// ---------------- K5: stress ----------------
__global__ void k_stress(const float* __restrict__ cell,
                         const float* __restrict__ virial,
                         float* __restrict__ stress, int n_images)
{
    const int t = blockIdx.x * blockDim.x + threadIdx.x;
    if (t >= n_images * 9) return;
    const float* c = &cell[(t / 9) * 9];
    const float crx = c[4]*c[8] - c[5]*c[7];
    const float cry = c[5]*c[6] - c[3]*c[8];
    const float crz = c[3]*c[7] - c[4]*c[6];
    const float vol = c[0]*crx + c[1]*cry + c[2]*crz;
    stress[t] = virial[t] * (-1.0f / vol);
}

// ---------------- fallback (round-1) path ----------------
__global__ __launch_bounds__(256) void edge_kernel_fb(
    const float* __restrict__ edge_diff, const float* __restrict__ dE_ddiff,
    const int2* __restrict__ edge_idx, const int* __restrict__ image_idx,
    float* __restrict__ forces, float* __restrict__ virial,
    int n_edges, int n_images)
{
    extern __shared__ float lds_v[];
    const int nv = n_images * 9;
    for (int t = threadIdx.x; t < nv; t += blockDim.x) lds_v[t] = 0.f;
    __syncthreads();
    const int stride = gridDim.x * blockDim.x;
    for (int e = blockIdx.x * blockDim.x + threadIdx.x; e < n_edges; e += stride) {
        const int2 ij = edge_idx[e];
        const int i = ij.x, j = ij.y;
        const float dx = dE_ddiff[3*e+0], dy = dE_ddiff[3*e+1], dz = dE_ddiff[3*e+2];
        unsafeAtomicAdd(&forces[3*i+0],  dx);
        unsafeAtomicAdd(&forces[3*i+1],  dy);
        unsafeAtomicAdd(&forces[3*i+2],  dz);
        unsafeAtomicAdd(&forces[3*j+0], -dx);
        unsafeAtomicAdd(&forces[3*j+1], -dy);
        unsafeAtomicAdd(&forces[3*j+2], -dz);
        const float ex = edge_diff[3*e+0], ey = edge_diff[3*e+1], ez = edge_diff[3*e+2];
        float* v = &lds_v[image_idx[i] * 9];
        atomicAdd(&v[0], ex*dx); atomicAdd(&v[1], ex*dy); atomicAdd(&v[2], ex*dz);
        atomicAdd(&v[3], ey*dx); atomicAdd(&v[4], ey*dy); atomicAdd(&v[5], ey*dz);
        atomicAdd(&v[6], ez*dx); atomicAdd(&v[7], ez*dy); atomicAdd(&v[8], ez*dz);
    }
    __syncthreads();
    for (int t = threadIdx.x; t < nv; t += blockDim.x) {
        const float val = lds_v[t];
        if (val != 0.f) unsafeAtomicAdd(&virial[t], val);
    }
}

extern "C" void kernel_launch(void* const* d_in, const int* in_sizes, int n_in,
                              void* d_out, int out_size, void* d_ws, size_t ws_size,
                              hipStream_t stream)
{
    const float* edge_diff = (const float*)d_in[0];
    const float* dE_ddiff  = (const float*)d_in[1];
    const float* cell      = (const float*)d_in[2];
    const int2*  edge_idx  = (const int2*)d_in[3];
    const int*   image_idx = (const int*)d_in[4];

    const int n_edges  = in_sizes[0] / 3;
    const int n_images = in_sizes[2] / 9;
    const int n_atoms  = in_sizes[4];
    const int nv       = n_images * 9;

    float* out    = (float*)d_out;
    float* forces = out;
    float* virial = out + (size_t)n_atoms * 3;
    float* stress = virial + nv;

    const int nb = (n_atoms + (1 << BASHIFT) - 1) >> BASHIFT;
    const int es = (n_edges + SLICES - 1) / SLICES;
    const uint total = (uint)(2 * (size_t)n_edges);

    const size_t entries_bytes = (size_t)total * sizeof(float4);
    const size_t counts_bytes  = (size_t)nb * SLICES * sizeof(uint);
    const size_t aux_bytes     = 2 * (size_t)NBCAP * sizeof(uint);
    const size_t need = entries_bytes + counts_bytes + aux_bytes;

    if (ws_size >= need && nb <= NBCAP && nv <= NVMAX) {
        float4* entries = (float4*)d_ws;
        uint*   offsets = (uint*)((char*)d_ws + entries_bytes);
        uint*   rowsum  = offsets + (size_t)nb * SLICES;
        uint*   rowoff  = rowsum + NBCAP;

        hipMemsetAsync(virial, 0, nv * sizeof(float), stream);

        k_count<<<SLICES, 1024, 0, stream>>>(edge_idx, offsets, n_edges, es, nb);
        k_rowsum<<<nb, SLICES, 0, stream>>>(offsets, rowsum);
        k_scan_rows<<<1, 1024, 0, stream>>>(rowsum, rowoff, nb);
        k_rowscan<<<nb, SLICES, 0, stream>>>(offsets, rowoff);
        k_scatter<<<SLICES, 1024, 0, stream>>>(edge_diff, dE_ddiff, edge_idx, image_idx,
                                               offsets, entries, virial, n_edges, es, nb, nv);
        k_gather<<<nb, 256, 0, stream>>>(entries, offsets, forces, n_atoms, nb, total);
        k_stress<<<(nv + 255) / 256, 256, 0, stream>>>(cell, virial, stress, n_images);
    } else {
        hipMemsetAsync(out, 0, ((size_t)n_atoms * 3 + nv) * sizeof(float), stream);
        edge_kernel_fb<<<2048, 256, nv * sizeof(float), stream>>>(
            edge_diff, dE_ddiff, edge_idx, image_idx, forces, virial, n_edges, n_images);
        k_stress<<<(nv + 255) / 256, 256, 0, stream>>>(cell, virial, stress, n_images);
    }
}